// Round 4
// baseline (856.009 us; speedup 1.0000x reference)
//
#include <hip/hip_runtime.h>
#include <cstdint>

#define LM1   3
#define BDIM  64
#define NROW  192
#define DDIM  512
#define NW    262144
#define NW4   65536
#define NT    1024

#define SSAMP 32768
#define CAPQ  6144
#define CAP3  14336
#define SEG0  0
#define SEG1  6144
#define SEG2  12288
#define SEG3  18432

#define H1OFF 32768     // hist: 4096 words
#define H2OFF 36864     // hist2: 2048 words
#define SBOFF 38912     // sbuf: 1024 words
#define CTOFF 39936     // ctrl: 64 words
#define LDSW  40000

// ---------- monotone float<->uint transform (total order) ----------
__device__ __forceinline__ uint32_t mono(float x) {
    uint32_t u = __float_as_uint(x);
    return (u & 0x80000000u) ? ~u : (u | 0x80000000u);
}
__device__ __forceinline__ float unmono(uint32_t u) {
    uint32_t v = (u & 0x80000000u) ? (u & 0x7FFFFFFFu) : ~u;
    return __uint_as_float(v);
}

// ---------- block "find bin containing rank" — shfl-scan version (3 barriers) ----------
__device__ void block_select(const uint32_t* hist, int nb, uint32_t rank,
                             uint32_t* sbuf, volatile uint32_t* out, int tid) {
    int per = (nb + NT - 1) / NT;
    int base = tid * per;
    uint32_t s = 0;
    for (int i = 0; i < per; ++i) { int idx = base + i; if (idx < nb) s += hist[idx]; }
    uint32_t p = s;
    int lane = tid & 63;
    #pragma unroll
    for (int off = 1; off < 64; off <<= 1) {
        uint32_t v = __shfl_up(p, off);
        if (lane >= off) p += v;
    }
    int w = tid >> 6;
    if (lane == 63) sbuf[w] = p;
    __syncthreads();
    if (tid == 0) {
        uint32_t acc = 0;
        for (int i = 0; i < 16; ++i) { uint32_t t = sbuf[i]; sbuf[16 + i] = acc; acc += t; }
    }
    __syncthreads();
    uint32_t excl = sbuf[16 + w] + p - s;
    if (rank >= excl && rank < excl + s) {
        uint32_t rem = rank - excl;
        for (int i = 0; i < per; ++i) {
            int idx = base + i;
            if (idx >= nb) break;
            uint32_t c = hist[idx];
            if (rem < c) { out[0] = (uint32_t)idx; out[1] = rem; break; }
            rem -= c;
        }
    }
    __syncthreads();
}

__device__ __forceinline__ uint32_t sel_key(uint32_t st, int mode, float med) {
    return mode ? __float_as_uint(fabsf(unmono(st) - med)) : st;
}

// ---------- exact rank-select among seg[0..cnt) via 3-pass LDS radix (11/11/10) ----------
__device__ uint32_t seg_select(const uint32_t* seg, uint32_t cnt, uint32_t rank,
                               int mode, float med,
                               uint32_t* hist2, uint32_t* sbuf,
                               volatile uint32_t* out2, int tid) {
    for (int i = tid; i < 2048; i += NT) hist2[i] = 0;
    __syncthreads();
    for (uint32_t i = tid; i < cnt; i += NT)
        atomicAdd(&hist2[sel_key(seg[i], mode, med) >> 21], 1u);
    __syncthreads();
    block_select(hist2, 2048, rank, sbuf, out2, tid);
    uint32_t b1 = out2[0], r1 = out2[1];
    __syncthreads();
    for (int i = tid; i < 2048; i += NT) hist2[i] = 0;
    __syncthreads();
    for (uint32_t i = tid; i < cnt; i += NT) {
        uint32_t k = sel_key(seg[i], mode, med);
        if ((k >> 21) == b1) atomicAdd(&hist2[(k >> 10) & 2047u], 1u);
    }
    __syncthreads();
    block_select(hist2, 2048, r1, sbuf, out2, tid);
    uint32_t b2 = out2[0], r2 = out2[1];
    __syncthreads();
    for (int i = tid; i < 1024; i += NT) hist2[i] = 0;
    __syncthreads();
    for (uint32_t i = tid; i < cnt; i += NT) {
        uint32_t k = sel_key(seg[i], mode, med);
        if ((k >> 21) == b1 && ((k >> 10) & 2047u) == b2)
            atomicAdd(&hist2[k & 1023u], 1u);
    }
    __syncthreads();
    block_select(hist2, 1024, r2, sbuf, out2, tid);
    uint32_t b3 = out2[0];
    __syncthreads();
    return (b1 << 21) + (b2 << 10) + b3;
}

// ---------- fallback: finish a rank with 2 global sweeps (slow, always correct) ----------
__device__ uint32_t refine_global(const float4* p4, float med, int mode,
                                  uint32_t b1, uint32_t rem,
                                  uint32_t* hist2, uint32_t* sbuf,
                                  volatile uint32_t* out2, int tid) {
    for (int i = tid; i < 2048; i += NT) hist2[i] = 0;
    __syncthreads();
    for (int it = 0; it < 64; ++it) {
        float4 v = p4[tid + it * NT];
        float xs[4] = {v.x, v.y, v.z, v.w};
        #pragma unroll
        for (int c = 0; c < 4; ++c) {
            uint32_t u = mode ? __float_as_uint(fabsf(xs[c] - med)) : mono(xs[c]);
            if ((u >> 20) == b1) atomicAdd(&hist2[(u >> 9) & 2047u], 1u);
        }
    }
    __syncthreads();
    block_select(hist2, 2048, rem, sbuf, out2, tid);
    uint32_t b2 = out2[0], r2 = out2[1];
    __syncthreads();
    for (int i = tid; i < 512; i += NT) hist2[i] = 0;
    __syncthreads();
    for (int it = 0; it < 64; ++it) {
        float4 v = p4[tid + it * NT];
        float xs[4] = {v.x, v.y, v.z, v.w};
        #pragma unroll
        for (int c = 0; c < 4; ++c) {
            uint32_t u = mode ? __float_as_uint(fabsf(xs[c] - med)) : mono(xs[c]);
            if ((u >> 20) == b1 && ((u >> 9) & 2047u) == b2)
                atomicAdd(&hist2[u & 511u], 1u);
        }
    }
    __syncthreads();
    block_select(hist2, 512, r2, sbuf, out2, tid);
    uint32_t b3 = out2[0];
    __syncthreads();
    return (b1 << 20) + (b2 << 9) + b3;
}

// ---------- fallback path: full 3-level histogram select (slow, always correct) ----------
__device__ void fb_path(const float4* p4, float* feat, int row,
                        uint32_t* lds, int tid) {
    uint32_t* histF  = lds;              // 4096
    uint32_t* hist2F = lds + 4096;       // 2048
    uint32_t* sbufF  = lds + 4096 + 2048;
    volatile uint32_t* outF = (volatile uint32_t*)(lds + CTOFF + 4);
    const uint32_t RANK6[6] = {65535u, 65536u, 131071u, 131072u, 196607u, 196608u};

    for (int i = tid; i < 4096; i += NT) histF[i] = 0;
    __syncthreads();
    for (int it = 0; it < 64; ++it) {
        float4 v = p4[tid + it * NT];
        float xs[4] = {v.x, v.y, v.z, v.w};
        #pragma unroll
        for (int c = 0; c < 4; ++c) atomicAdd(&histF[mono(xs[c]) >> 20], 1u);
    }
    __syncthreads();
    uint32_t bins[6], rems[6];
    for (int k = 0; k < 6; ++k) {
        block_select(histF, 4096, RANK6[k], sbufF, outF, tid);
        bins[k] = outF[0]; rems[k] = outF[1];
        __syncthreads();
    }
    float svv[6];
    for (int k = 0; k < 6; ++k)
        svv[k] = unmono(refine_global(p4, 0.f, 0, bins[k], rems[k], hist2F, sbufF, outF, tid));
    if (tid == 0) {
        float* f = feat + row * 16;
        f[0] = svv[2];
        f[3] = 0.25f * svv[0] + 0.75f * svv[1];
        f[4] = 0.5f  * (svv[2] + svv[3]);
        f[5] = 0.75f * svv[4] + 0.25f * svv[5];
    }
    float med = svv[2];
    __syncthreads();
    for (int i = tid; i < 4096; i += NT) histF[i] = 0;
    __syncthreads();
    for (int it = 0; it < 64; ++it) {
        float4 v = p4[tid + it * NT];
        float xs[4] = {v.x, v.y, v.z, v.w};
        #pragma unroll
        for (int c = 0; c < 4; ++c)
            atomicAdd(&histF[__float_as_uint(fabsf(xs[c] - med)) >> 20], 1u);
    }
    __syncthreads();
    block_select(histF, 4096, 131071u, sbufF, outF, tid);
    uint32_t mb = outF[0], mr = outF[1];
    __syncthreads();
    uint32_t mu = refine_global(p4, med, 1, mb, mr, hist2F, sbufF, outF, tid);
    if (tid == 0) feat[row * 16 + 1] = __uint_as_float(mu);
}

// ---------- w-row robust stats: single full sweep + sample brackets ----------
__global__ __launch_bounds__(NT) void wstats_kernel(const float* __restrict__ wsrc,
                                                    float* __restrict__ feat) {
    const int row = blockIdx.x;
    const int tid = threadIdx.x;
    const float* __restrict__ src = wsrc + (size_t)row * NW;
    const float4* __restrict__ p4 = (const float4*)src;

    __shared__ uint32_t lds[LDSW];
    __shared__ float fctrl[8];
    uint32_t* hist  = lds + H1OFF;
    uint32_t* hist2 = lds + H2OFF;
    uint32_t* sbuf  = lds + SBOFF;
    uint32_t* ctrl  = lds + CTOFF;
    volatile uint32_t* out2 = (volatile uint32_t*)(ctrl + 4);

    // ---- P0/P1: sample every 8th element (also warms L2/L3 with full row) ----
    for (int i = tid; i < 4096; i += NT) hist[i] = 0;
    __syncthreads();
    for (int k = 0; k < 32; ++k) {
        int i = tid + k * NT;
        float x = src[(size_t)i * 8];
        uint32_t u = mono(x);
        lds[i] = u;
        atomicAdd(&hist[u >> 20], 1u);
    }
    __syncthreads();

    // ---- P2: 6 bracket endpoints from sample order statistics (level-2 bin edges) ----
    // sample ranks: q25 8192±274, med 16384±317, q75 24576±274 (3.5 sigma)
    const uint32_t EPRANK[6] = {7918u, 8466u, 16067u, 16701u, 24302u, 24850u};
    for (int e = 0; e < 6; ++e) {
        block_select(hist, 4096, EPRANK[e], sbuf, out2, tid);
        uint32_t b1 = out2[0], r1 = out2[1];
        __syncthreads();
        for (int i = tid; i < 2048; i += NT) hist2[i] = 0;
        __syncthreads();
        for (int k = 0; k < 32; ++k) {
            uint32_t u = lds[tid + k * NT];
            if ((u >> 20) == b1) atomicAdd(&hist2[(u >> 9) & 2047u], 1u);
        }
        __syncthreads();
        block_select(hist2, 2048, r1, sbuf, out2, tid);
        uint32_t b2 = out2[0];
        if (tid == 0) ctrl[6 + e] = (b1 << 20) + ((b2 + (uint32_t)(e & 1)) << 9);
        __syncthreads();
    }

    // ---- P3: MAD bracket from sample of |s - m0| ----
    if (tid == 0) {
        float lo = unmono(ctrl[8]), hi = unmono(ctrl[9]);
        fctrl[0] = 0.5f * (lo + hi);   // m0
        fctrl[1] = 0.5f * (hi - lo);   // delta >= |med - m0| (if med in bracket)
    }
    __syncthreads();
    const float m0 = fctrl[0];
    for (int i = tid; i < 4096; i += NT) hist[i] = 0;
    __syncthreads();
    for (int k = 0; k < 32; ++k) {
        uint32_t tb = __float_as_uint(fabsf(unmono(lds[tid + k * NT]) - m0));
        atomicAdd(&hist[tb >> 20], 1u);
    }
    __syncthreads();
    const uint32_t MRANK[2] = {16067u, 16701u};
    for (int e = 0; e < 2; ++e) {
        block_select(hist, 4096, MRANK[e], sbuf, out2, tid);
        uint32_t b1 = out2[0], r1 = out2[1];
        __syncthreads();
        for (int i = tid; i < 2048; i += NT) hist2[i] = 0;
        __syncthreads();
        for (int k = 0; k < 32; ++k) {
            uint32_t tb = __float_as_uint(fabsf(unmono(lds[tid + k * NT]) - m0));
            if ((tb >> 20) == b1) atomicAdd(&hist2[(tb >> 9) & 2047u], 1u);
        }
        __syncthreads();
        block_select(hist2, 2048, r1, sbuf, out2, tid);
        uint32_t b2 = out2[0];
        if (tid == 0) ctrl[18 + e] = (b1 << 20) + ((b2 + (uint32_t)(e & 1)) << 9);
        __syncthreads();
    }
    if (tid == 0) {
        float dwin = fctrl[1] * 1.01f;
        fctrl[2] = fmaxf(__uint_as_float(ctrl[18]) - dwin, 0.0f);  // AwinLo
        fctrl[3] = __uint_as_float(ctrl[19]) + dwin;               // AwinHi
        ctrl[0] = 0; ctrl[1] = 0; ctrl[2] = 0; ctrl[3] = 0;        // cursors
        ctrl[12] = 0;                                              // fail
    }
    __syncthreads();

    // ---- P4: THE single full sweep — counts in registers, rare LDS collect ----
    const uint32_t L25 = ctrl[6],  W25 = ctrl[7]  - ctrl[6];
    const uint32_t Lm  = ctrl[8],  Wm  = ctrl[9]  - ctrl[8];
    const uint32_t L75 = ctrl[10], W75 = ctrl[11] - ctrl[10];
    const float AwinLo = fctrl[2], AwinHi = fctrl[3];
    float sum = 0.f;
    uint32_t umin = 0xFFFFFFFFu, umax = 0u;
    uint32_t c25 = 0, cm = 0, c75 = 0, cmad = 0;
    for (int it = 0; it < 64; ++it) {
        float4 v = p4[tid + it * NT];
        float xs[4] = {v.x, v.y, v.z, v.w};
        #pragma unroll
        for (int c = 0; c < 4; ++c) {
            float x = xs[c];
            uint32_t u = mono(x);
            sum += x;
            umin = umin < u ? umin : u;
            umax = umax > u ? umax : u;
            c25 += (u < L25); cm += (u < Lm); c75 += (u < L75);
            if (u - L25 < W25) { uint32_t p = atomicAdd(&ctrl[0], 1u); if (p < CAPQ) lds[SEG0 + p] = u; }
            if (u - Lm  < Wm ) { uint32_t p = atomicAdd(&ctrl[1], 1u); if (p < CAPQ) lds[SEG1 + p] = u; }
            if (u - L75 < W75) { uint32_t p = atomicAdd(&ctrl[2], 1u); if (p < CAPQ) lds[SEG2 + p] = u; }
            float t = fabsf(x - m0);
            cmad += (t < AwinLo);
            if (t >= AwinLo && t <= AwinHi) { uint32_t p = atomicAdd(&ctrl[3], 1u); if (p < CAP3) lds[SEG3 + p] = u; }
        }
    }
    __syncthreads();

    // ---- P5: reductions (wave shfl + tiny serial) ----
    {
        int lane = tid & 63, w = tid >> 6;
        #pragma unroll
        for (int off = 32; off > 0; off >>= 1) {
            sum  += __shfl_down(sum, off);
            uint32_t t;
            t = __shfl_down(umin, off); umin = umin < t ? umin : t;
            t = __shfl_down(umax, off); umax = umax > t ? umax : t;
            c25 += __shfl_down(c25, off);
            cm  += __shfl_down(cm, off);
            c75 += __shfl_down(c75, off);
            cmad+= __shfl_down(cmad, off);
        }
        float* fsb = (float*)sbuf;
        if (lane == 0) {
            fsb[w * 8 + 0] = sum;
            sbuf[w * 8 + 1] = umin; sbuf[w * 8 + 2] = umax;
            sbuf[w * 8 + 3] = c25;  sbuf[w * 8 + 4] = cm;
            sbuf[w * 8 + 5] = c75;  sbuf[w * 8 + 6] = cmad;
        }
        __syncthreads();
        if (tid == 0) { float s = 0; for (int i = 0; i < 16; ++i) s += fsb[i * 8]; feat[row * 16 + 14] = s * (1.0f / (float)NW); }
        if (tid == 1) { uint32_t m = 0xFFFFFFFFu; for (int i = 0; i < 16; ++i) { uint32_t t = sbuf[i * 8 + 1]; m = m < t ? m : t; } feat[row * 16 + 2] = unmono(m); }
        if (tid == 2) { uint32_t m = 0u; for (int i = 0; i < 16; ++i) { uint32_t t = sbuf[i * 8 + 2]; m = m > t ? m : t; } feat[row * 16 + 6] = unmono(m); }
        if (tid >= 3 && tid <= 6) { uint32_t s = 0; for (int i = 0; i < 16; ++i) s += sbuf[i * 8 + tid]; ctrl[10 + tid] = s; }  // ctrl[13..16]
        if (tid == 7) feat[row * 16 + 15] = 0.0f;
    }
    __syncthreads();

    // ---- P6: validity ----
    if (tid == 0) {
        int C25 = (int)ctrl[13], Cm = (int)ctrl[14], C75 = (int)ctrl[15], Cmad = (int)ctrl[16];
        int n0 = (int)(ctrl[0] < CAPQ ? ctrl[0] : CAPQ);
        int n1 = (int)(ctrl[1] < CAPQ ? ctrl[1] : CAPQ);
        int n2 = (int)(ctrl[2] < CAPQ ? ctrl[2] : CAPQ);
        int n3 = (int)(ctrl[3] < CAP3 ? ctrl[3] : CAP3);
        int fail = (ctrl[0] > CAPQ) || (ctrl[1] > CAPQ) || (ctrl[2] > CAPQ) || (ctrl[3] > CAP3)
                || (C25 > 65535)  || (65536  - C25 >= n0)
                || (Cm  > 131071) || (131072 - Cm  >= n1)
                || (C75 > 196607) || (196608 - C75 >= n2)
                || (Cmad > 131071)|| (131071 - Cmad >= n3);
        ctrl[12] = (uint32_t)fail;
    }
    __syncthreads();

    if (ctrl[12]) { fb_path(p4, feat, row, lds, tid); return; }

    // ---- P7: exact selects from collected segments ----
    const uint32_t C25 = ctrl[13], Cm = ctrl[14], C75 = ctrl[15], Cmad = ctrl[16];
    const uint32_t n0 = ctrl[0], n1 = ctrl[1], n2 = ctrl[2], n3 = ctrl[3];
    uint32_t k25a = seg_select(lds + SEG0, n0, 65535u  - C25, 0, 0.f, hist2, sbuf, out2, tid);
    uint32_t k25b = seg_select(lds + SEG0, n0, 65536u  - C25, 0, 0.f, hist2, sbuf, out2, tid);
    uint32_t kma  = seg_select(lds + SEG1, n1, 131071u - Cm,  0, 0.f, hist2, sbuf, out2, tid);
    uint32_t kmb  = seg_select(lds + SEG1, n1, 131072u - Cm,  0, 0.f, hist2, sbuf, out2, tid);
    uint32_t k75a = seg_select(lds + SEG2, n2, 196607u - C75, 0, 0.f, hist2, sbuf, out2, tid);
    uint32_t k75b = seg_select(lds + SEG2, n2, 196608u - C75, 0, 0.f, hist2, sbuf, out2, tid);
    float med = unmono(kma);
    uint32_t kmad = seg_select(lds + SEG3, n3, 131071u - Cmad, 1, med, hist2, sbuf, out2, tid);
    float madv = __uint_as_float(kmad);
    float dchk = fctrl[1] * 1.02f + 1e-12f;
    bool bad = !(madv > fctrl[2] + dchk && madv < fctrl[3] - dchk);
    if (bad) { fb_path(p4, feat, row, lds, tid); return; }
    if (tid == 0) {
        float* f = feat + row * 16;
        f[0] = med;
        f[1] = madv;
        f[3] = 0.25f * unmono(k25a) + 0.75f * unmono(k25b);
        f[4] = 0.5f  * (med + unmono(kmb));
        f[5] = 0.75f * unmono(k75a) + 0.25f * unmono(k75b);
    }
}

// ---------- in-LDS bitonic sort of 512 floats, 256 threads ----------
__device__ void bitonic512(float* a, int tid) {
    for (int k = 2; k <= 512; k <<= 1) {
        for (int j = k >> 1; j > 0; j >>= 1) {
            __syncthreads();
            for (int i = tid; i < 512; i += 256) {
                int ixj = i ^ j;
                if (ixj > i) {
                    float x = a[i], y = a[ixj];
                    bool up = ((i & k) == 0);
                    if ((x > y) == up) { a[i] = y; a[ixj] = x; }
                }
            }
        }
    }
    __syncthreads();
}

// ---------- tail: b-row stats + MLP head fused, one block per (l,b) row ----------
__global__ __launch_bounds__(256) void tail_kernel(
    const float* __restrict__ bsrc, const float* __restrict__ feat,
    const float* __restrict__ fc1_w, const float* __restrict__ fc1_b,
    const float* __restrict__ ln_w,  const float* __restrict__ ln_b,
    const float* __restrict__ gate_w, const float* __restrict__ gate_b,
    const float* __restrict__ fco_w,  const float* __restrict__ fco_b,
    const float* __restrict__ scale,  float* __restrict__ out) {
    const int row = blockIdx.x;
    const int tid = threadIdx.x;
    const int l = row >> 6;
    __shared__ float a[512], d[512];
    __shared__ float x[16], h[64], hg[64], stats[2];

    if (tid < 7)       x[tid] = feat[row * 16 + tid];
    else if (tid == 7) x[14]  = feat[row * 16 + 14];
    else if (tid == 8) x[15]  = 0.0f;

    const float* p = bsrc + (size_t)row * 512;
    for (int i = tid; i < 512; i += 256) a[i] = p[i];
    bitonic512(a, tid);
    const float bmed = a[255];
    if (tid == 0) {
        x[7]  = bmed;
        x[9]  = a[0];
        x[10] = 0.25f * a[127] + 0.75f * a[128];
        x[11] = 0.5f  * (a[255] + a[256]);
        x[12] = 0.75f * a[383] + 0.25f * a[384];
        x[13] = a[511];
    }
    __syncthreads();
    for (int i = tid; i < 512; i += 256) d[i] = fabsf(a[i] - bmed);
    bitonic512(d, tid);
    if (tid == 0) x[8] = d[255];
    __syncthreads();

    if (tid == 0) {
        float mu = 0.f;
        for (int i = 0; i < 16; ++i) mu += x[i];
        mu *= (1.f / 16.f);
        float var = 0.f;
        for (int i = 0; i < 16; ++i) { float dd = x[i] - mu; var += dd * dd; }
        var *= (1.f / 16.f);
        stats[0] = mu; stats[1] = rsqrtf(var + 1e-5f);
    }
    __syncthreads();
    if (tid < 16) x[tid] = (x[tid] - stats[0]) * stats[1];
    __syncthreads();
    if (tid < 64) {
        const float* w = fc1_w + ((size_t)l * 64 + tid) * 16;
        float acc = fc1_b[l * 64 + tid];
        #pragma unroll
        for (int i = 0; i < 16; ++i) acc += x[i] * w[i];
        h[tid] = acc;
    }
    __syncthreads();
    if (tid == 0) {
        float mu = 0.f;
        for (int i = 0; i < 64; ++i) mu += h[i];
        mu *= (1.f / 64.f);
        float var = 0.f;
        for (int i = 0; i < 64; ++i) { float dd = h[i] - mu; var += dd * dd; }
        var *= (1.f / 64.f);
        stats[0] = mu; stats[1] = rsqrtf(var + 1e-5f);
    }
    __syncthreads();
    if (tid < 64) {
        float v = (h[tid] - stats[0]) * stats[1] * ln_w[l * 64 + tid] + ln_b[l * 64 + tid];
        h[tid] = 0.5f * v * (1.0f + erff(v * 0.70710678118654752f));
    }
    __syncthreads();
    if (tid < 64) {
        const float* w = gate_w + ((size_t)l * 64 + tid) * 64;
        float acc = gate_b[l * 64 + tid];
        #pragma unroll
        for (int i = 0; i < 64; ++i) acc += h[i] * w[i];
        float g = 1.0f / (1.0f + expf(-acc));
        hg[tid] = h[tid] * g;
    }
    __syncthreads();
    const float sc = scale[l];
    for (int o = tid; o < 512; o += 256) {
        const float* w = fco_w + ((size_t)l * 512 + o) * 64;
        float acc = fco_b[l * 512 + o];
        #pragma unroll
        for (int i = 0; i < 64; ++i) acc += hg[i] * w[i];
        out[(size_t)row * 512 + o] = sinf(acc) * sc + 1.0f;
    }
}

extern "C" void kernel_launch(void* const* d_in, const int* in_sizes, int n_in,
                              void* d_out, int out_size, void* d_ws, size_t ws_size,
                              hipStream_t stream) {
    const float* ws_in  = (const float*)d_in[0];
    const float* bs_in  = (const float*)d_in[1];
    const float* fc1_w  = (const float*)d_in[4];
    const float* fc1_b  = (const float*)d_in[5];
    const float* ln_w   = (const float*)d_in[6];
    const float* ln_b   = (const float*)d_in[7];
    const float* gate_w = (const float*)d_in[8];
    const float* gate_b = (const float*)d_in[9];
    const float* fco_w  = (const float*)d_in[10];
    const float* fco_b  = (const float*)d_in[11];
    const float* scale  = (const float*)d_in[12];
    float* out  = (float*)d_out;
    float* feat = (float*)d_ws;

    hipLaunchKernelGGL(wstats_kernel, dim3(NROW), dim3(NT), 0, stream, ws_in, feat);
    hipLaunchKernelGGL(tail_kernel, dim3(NROW), dim3(256), 0, stream,
                       bs_in, feat, fc1_w, fc1_b, ln_w, ln_b, gate_w, gate_b,
                       fco_w, fco_b, scale, out);
}

// Round 5
// 458.931 us; speedup vs baseline: 1.8652x; 1.8652x over previous
//
#include <hip/hip_runtime.h>
#include <cstdint>

#define NROW 192
#define NW   262144
#define NW4  65536
#define NT   1024
#define QCAP 1024
#define MCAP 6144

// ---------- monotone float<->uint transform (total order) ----------
__device__ __forceinline__ uint32_t mono(float x) {
    uint32_t u = __float_as_uint(x);
    return (u & 0x80000000u) ? ~u : (u | 0x80000000u);
}
__device__ __forceinline__ float unmono(uint32_t u) {
    uint32_t v = (u & 0x80000000u) ? (u & 0x7FFFFFFFu) : ~u;
    return __uint_as_float(v);
}
// linear-in-value bin; MUST be the same code in hist and collect sweeps
__device__ __forceinline__ int binof(float x, float lo, float s) {
    float d = (x - lo) * s;
    d = fminf(fmaxf(d, 0.0f), 4095.0f);
    return (int)d;
}

// ---------- block "find bin containing rank" (proven R4) ----------
__device__ void block_select(const uint32_t* hist, int nb, uint32_t rank,
                             uint32_t* sbuf, volatile uint32_t* out, int tid) {
    int per = (nb + NT - 1) / NT;
    int base = tid * per;
    uint32_t s = 0;
    for (int i = 0; i < per; ++i) { int idx = base + i; if (idx < nb) s += hist[idx]; }
    uint32_t p = s;
    int lane = tid & 63;
    #pragma unroll
    for (int off = 1; off < 64; off <<= 1) {
        uint32_t v = __shfl_up(p, off);
        if (lane >= off) p += v;
    }
    int w = tid >> 6;
    if (lane == 63) sbuf[w] = p;
    __syncthreads();
    if (tid == 0) {
        uint32_t acc = 0;
        for (int i = 0; i < 16; ++i) { uint32_t t = sbuf[i]; sbuf[16 + i] = acc; acc += t; }
    }
    __syncthreads();
    uint32_t excl = sbuf[16 + w] + p - s;
    if (rank >= excl && rank < excl + s) {
        uint32_t rem = rank - excl;
        for (int i = 0; i < per; ++i) {
            int idx = base + i;
            if (idx >= nb) break;
            uint32_t c = hist[idx];
            if (rem < c) { out[0] = (uint32_t)idx; out[1] = rem; break; }
            rem -= c;
        }
    }
    __syncthreads();
}

// ---------- exact rank-select among seg[0..cnt) keys, 3-pass LDS radix 11/11/10 ----------
__device__ uint32_t seg_select(const uint32_t* seg, uint32_t cnt, uint32_t rank,
                               uint32_t* hist2, uint32_t* sbuf,
                               volatile uint32_t* out2, int tid) {
    for (int i = tid; i < 2048; i += NT) hist2[i] = 0;
    __syncthreads();
    for (uint32_t i = tid; i < cnt; i += NT) atomicAdd(&hist2[seg[i] >> 21], 1u);
    __syncthreads();
    block_select(hist2, 2048, rank, sbuf, out2, tid);
    uint32_t b1 = out2[0], r1 = out2[1];
    __syncthreads();
    for (int i = tid; i < 2048; i += NT) hist2[i] = 0;
    __syncthreads();
    for (uint32_t i = tid; i < cnt; i += NT) {
        uint32_t k = seg[i];
        if ((k >> 21) == b1) atomicAdd(&hist2[(k >> 10) & 2047u], 1u);
    }
    __syncthreads();
    block_select(hist2, 2048, r1, sbuf, out2, tid);
    uint32_t b2 = out2[0], r2 = out2[1];
    __syncthreads();
    for (int i = tid; i < 1024; i += NT) hist2[i] = 0;
    __syncthreads();
    for (uint32_t i = tid; i < cnt; i += NT) {
        uint32_t k = seg[i];
        if ((k >> 21) == b1 && ((k >> 10) & 2047u) == b2)
            atomicAdd(&hist2[k & 1023u], 1u);
    }
    __syncthreads();
    block_select(hist2, 1024, r2, sbuf, out2, tid);
    uint32_t b3 = out2[0];
    __syncthreads();
    return (b1 << 21) + (b2 << 10) + b3;
}

// ---------- fallback: finish a rank with 2 global sweeps (12-bit mono, proven) ----------
__device__ uint32_t refine_global(const float4* p4, float med, int mode,
                                  uint32_t b1, uint32_t rem,
                                  uint32_t* hist2, uint32_t* sbuf,
                                  volatile uint32_t* out2, int tid) {
    for (int i = tid; i < 2048; i += NT) hist2[i] = 0;
    __syncthreads();
    for (int it = 0; it < 64; ++it) {
        float4 v = p4[tid + it * NT];
        float xs[4] = {v.x, v.y, v.z, v.w};
        #pragma unroll
        for (int c = 0; c < 4; ++c) {
            uint32_t u = mode ? __float_as_uint(fabsf(xs[c] - med)) : mono(xs[c]);
            if ((u >> 20) == b1) atomicAdd(&hist2[(u >> 9) & 2047u], 1u);
        }
    }
    __syncthreads();
    block_select(hist2, 2048, rem, sbuf, out2, tid);
    uint32_t b2 = out2[0], r2 = out2[1];
    __syncthreads();
    for (int i = tid; i < 512; i += NT) hist2[i] = 0;
    __syncthreads();
    for (int it = 0; it < 64; ++it) {
        float4 v = p4[tid + it * NT];
        float xs[4] = {v.x, v.y, v.z, v.w};
        #pragma unroll
        for (int c = 0; c < 4; ++c) {
            uint32_t u = mode ? __float_as_uint(fabsf(xs[c] - med)) : mono(xs[c]);
            if ((u >> 20) == b1 && ((u >> 9) & 2047u) == b2)
                atomicAdd(&hist2[u & 511u], 1u);
        }
    }
    __syncthreads();
    block_select(hist2, 512, r2, sbuf, out2, tid);
    uint32_t b3 = out2[0];
    __syncthreads();
    return (b1 << 20) + (b2 << 9) + b3;
}

// ---------- fallback path: full 12-bit 3-level select (slow, always correct) ----------
__device__ void fb_path(const float4* p4, float* feat, int row,
                        uint32_t* hist, uint32_t* hist2, uint32_t* sbuf,
                        volatile uint32_t* out2, int tid) {
    const uint32_t RANK6[6] = {65535u, 65536u, 131071u, 131072u, 196607u, 196608u};
    for (int i = tid; i < 4096; i += NT) hist[i] = 0;
    __syncthreads();
    for (int it = 0; it < 64; ++it) {
        float4 v = p4[tid + it * NT];
        float xs[4] = {v.x, v.y, v.z, v.w};
        #pragma unroll
        for (int c = 0; c < 4; ++c) atomicAdd(&hist[mono(xs[c]) >> 20], 1u);
    }
    __syncthreads();
    uint32_t bins[6], rems[6];
    for (int k = 0; k < 6; ++k) {
        block_select(hist, 4096, RANK6[k], sbuf, out2, tid);
        bins[k] = out2[0]; rems[k] = out2[1];
        __syncthreads();
    }
    float svv[6];
    for (int k = 0; k < 6; ++k)
        svv[k] = unmono(refine_global(p4, 0.f, 0, bins[k], rems[k], hist2, sbuf, out2, tid));
    if (tid == 0) {
        float* f = feat + row * 16;
        f[0] = svv[2];
        f[3] = 0.25f * svv[0] + 0.75f * svv[1];
        f[4] = 0.5f  * (svv[2] + svv[3]);
        f[5] = 0.75f * svv[4] + 0.25f * svv[5];
    }
    float med = svv[2];
    __syncthreads();
    for (int i = tid; i < 4096; i += NT) hist[i] = 0;
    __syncthreads();
    for (int it = 0; it < 64; ++it) {
        float4 v = p4[tid + it * NT];
        float xs[4] = {v.x, v.y, v.z, v.w};
        #pragma unroll
        for (int c = 0; c < 4; ++c)
            atomicAdd(&hist[__float_as_uint(fabsf(xs[c] - med)) >> 20], 1u);
    }
    __syncthreads();
    block_select(hist, 4096, 131071u, sbuf, out2, tid);
    uint32_t mb = out2[0], mr = out2[1];
    __syncthreads();
    uint32_t mu = refine_global(p4, med, 1, mb, mr, hist2, sbuf, out2, tid);
    if (tid == 0) feat[row * 16 + 1] = __uint_as_float(mu);
}

// ---------- w-row robust stats: 4 cheap sweeps with linear-value bins ----------
__global__ __launch_bounds__(NT) void wstats_kernel(const float* __restrict__ wsrc,
                                                    float* __restrict__ feat) {
    const int row = blockIdx.x;
    const int tid = threadIdx.x;
    const float4* __restrict__ p4 = (const float4*)(wsrc + (size_t)row * NW);

    __shared__ uint32_t hist[4096];
    __shared__ uint32_t hist2[2048];
    __shared__ uint32_t sbuf[1024];
    __shared__ uint32_t segs[MCAP];      // 6x1024 quantile segs, reused as MAD seg
    __shared__ uint32_t ctrl[48];
    __shared__ float fctrl[8];
    volatile uint32_t* out2 = (volatile uint32_t*)(ctrl + 40);

    const int lane = tid & 63, w = tid >> 6;
    float* fsb = (float*)sbuf;

    // ---- P0: contiguous prefix sample (32768 floats) -> linear-bin range ----
    {
        float smin = 1e30f, smax = -1e30f;
        #pragma unroll
        for (int k = 0; k < 8; ++k) {
            float4 v = p4[tid + k * NT];
            smin = fminf(smin, fminf(fminf(v.x, v.y), fminf(v.z, v.w)));
            smax = fmaxf(smax, fmaxf(fmaxf(v.x, v.y), fmaxf(v.z, v.w)));
        }
        #pragma unroll
        for (int off = 32; off > 0; off >>= 1) {
            smin = fminf(smin, __shfl_down(smin, off));
            smax = fmaxf(smax, __shfl_down(smax, off));
        }
        if (lane == 0) { fsb[w * 2] = smin; fsb[w * 2 + 1] = smax; }
        __syncthreads();
        if (tid == 0) {
            float mn = 1e30f, mx = -1e30f;
            for (int i = 0; i < 16; ++i) { mn = fminf(mn, fsb[i * 2]); mx = fmaxf(mx, fsb[i * 2 + 1]); }
            float span = mx - mn;
            float lo = mn - 0.0625f * span;
            float s = (span > 0.f) ? 4096.0f / (span * 1.125f) : 0.0f;
            fctrl[0] = lo; fctrl[1] = s;
        }
        __syncthreads();
    }
    const float blo = fctrl[0], bsc = fctrl[1];

    // ---- S1: full sweep — linear hist + sum + exact min/max (reg) ----
    for (int i = tid; i < 4096; i += NT) hist[i] = 0;
    __syncthreads();
    {
        float sum = 0.f, fmn = 1e30f, fmx = -1e30f;
        for (int it = 0; it < 64; it += 8) {
            float4 a[8];
            #pragma unroll
            for (int j = 0; j < 8; ++j) a[j] = p4[tid + (it + j) * NT];
            #pragma unroll
            for (int j = 0; j < 8; ++j) {
                float xs[4] = {a[j].x, a[j].y, a[j].z, a[j].w};
                #pragma unroll
                for (int c = 0; c < 4; ++c) {
                    float x = xs[c];
                    sum += x;
                    fmn = fminf(fmn, x);
                    fmx = fmaxf(fmx, x);
                    atomicAdd(&hist[binof(x, blo, bsc)], 1u);
                }
            }
        }
        #pragma unroll
        for (int off = 32; off > 0; off >>= 1) {
            sum += __shfl_down(sum, off);
            fmn = fminf(fmn, __shfl_down(fmn, off));
            fmx = fmaxf(fmx, __shfl_down(fmx, off));
        }
        __syncthreads();   // sbuf free (P0 done)
        if (lane == 0) { fsb[w * 4] = sum; fsb[w * 4 + 1] = fmn; fsb[w * 4 + 2] = fmx; }
        __syncthreads();
        if (tid == 0) { float s = 0; for (int i = 0; i < 16; ++i) s += fsb[i * 4]; feat[row * 16 + 14] = s * (1.0f / (float)NW); }
        if (tid == 1) { float m = 1e30f;  for (int i = 0; i < 16; ++i) m = fminf(m, fsb[i * 4 + 1]); feat[row * 16 + 2] = m; fctrl[2] = m; }
        if (tid == 2) { float M = -1e30f; for (int i = 0; i < 16; ++i) M = fmaxf(M, fsb[i * 4 + 2]); feat[row * 16 + 6] = M; fctrl[3] = M; }
        if (tid == 3) feat[row * 16 + 15] = 0.0f;
        __syncthreads();
    }

    // ---- P2: level-1 selects for the 6 interior ranks ----
    const uint32_t RANKS[6] = {65535u, 65536u, 131071u, 131072u, 196607u, 196608u};
    for (int k = 0; k < 6; ++k) {
        block_select(hist, 4096, RANKS[k], sbuf, out2, tid);
        if (tid == 0) { ctrl[12 + k] = out2[0]; ctrl[18 + k] = out2[1]; }
        __syncthreads();
    }
    if (tid == 0) {
        uint32_t nd = 0;
        for (int k = 0; k < 6; ++k) {
            uint32_t b = ctrl[12 + k];
            int j = -1;
            for (uint32_t t = 0; t < nd; ++t) if (ctrl[24 + t] == b) { j = (int)t; break; }
            if (j < 0) { j = (int)nd; ctrl[24 + nd] = b; nd++; }
            ctrl[32 + k] = (uint32_t)j;
        }
        ctrl[10] = nd; ctrl[11] = 0;
        for (int j = 0; j < 6; ++j) ctrl[j] = 0;   // cursors
    }
    __syncthreads();
    const uint32_t nd = ctrl[10];
    // bin -> (seg idx + 1) byte table in sbuf
    sbuf[tid] = 0; sbuf[tid + (4096 - NT) ? 0 : 0] = sbuf[tid]; // (4096 bytes = 1024 words)
    __syncthreads();
    if (tid < (int)nd) ((uint8_t*)sbuf)[ctrl[24 + tid]] = (uint8_t)(tid + 1);
    __syncthreads();

    // ---- S2: full sweep — collect candidate-bin values (rare) ----
    {
        const uint8_t* tbl = (const uint8_t*)sbuf;
        for (int it = 0; it < 64; it += 8) {
            float4 a[8];
            #pragma unroll
            for (int j = 0; j < 8; ++j) a[j] = p4[tid + (it + j) * NT];
            #pragma unroll
            for (int j = 0; j < 8; ++j) {
                float xs[4] = {a[j].x, a[j].y, a[j].z, a[j].w};
                #pragma unroll
                for (int c = 0; c < 4; ++c) {
                    float x = xs[c];
                    uint32_t m = tbl[binof(x, blo, bsc)];
                    if (m) {
                        uint32_t jj = m - 1;
                        uint32_t pos = atomicAdd(&ctrl[jj], 1u);
                        if (pos < QCAP) segs[jj * QCAP + pos] = mono(x);
                    }
                }
            }
        }
    }
    __syncthreads();
    if (tid == 0) {
        uint32_t fail = 0;
        for (uint32_t j = 0; j < nd; ++j)
            if (ctrl[j] > QCAP || ctrl[j] != hist[ctrl[24 + j]]) fail = 1;
        ctrl[11] = fail;
    }
    __syncthreads();
    if (ctrl[11]) { fb_path(p4, feat, row, hist, hist2, sbuf, out2, tid); return; }

    // ---- P4: exact quantile selects from tiny segments ----
    float sv[6];
    for (int k = 0; k < 6; ++k) {
        uint32_t j = ctrl[32 + k];
        sv[k] = unmono(seg_select(segs + j * QCAP, ctrl[j], ctrl[18 + k],
                                  hist2, sbuf, out2, tid));
    }
    const float med = sv[2];
    if (tid == 0) {
        float* f = feat + row * 16;
        f[0] = med;
        f[3] = 0.25f * sv[0] + 0.75f * sv[1];
        f[4] = 0.5f  * (sv[2] + sv[3]);
        f[5] = 0.75f * sv[4] + 0.25f * sv[5];
    }

    // ---- S3: full sweep — linear hist of t=|x-med| on [0, tmax] ----
    const float tmax = fmaxf(fctrl[3] - med, med - fctrl[2]);
    const float tsc = (tmax > 0.f) ? 4096.0f / tmax : 0.0f;
    for (int i = tid; i < 4096; i += NT) hist[i] = 0;
    __syncthreads();
    for (int it = 0; it < 64; it += 8) {
        float4 a[8];
        #pragma unroll
        for (int j = 0; j < 8; ++j) a[j] = p4[tid + (it + j) * NT];
        #pragma unroll
        for (int j = 0; j < 8; ++j) {
            float xs[4] = {a[j].x, a[j].y, a[j].z, a[j].w};
            #pragma unroll
            for (int c = 0; c < 4; ++c)
                atomicAdd(&hist[binof(fabsf(xs[c] - med), 0.0f, tsc)], 1u);
        }
    }
    __syncthreads();
    block_select(hist, 4096, 131071u, sbuf, out2, tid);
    const uint32_t mbin = out2[0], mrem = out2[1];
    if (tid == 0) ctrl[8] = 0;
    __syncthreads();

    // ---- S4: full sweep — collect MAD bin (t bit patterns) ----
    for (int it = 0; it < 64; it += 8) {
        float4 a[8];
        #pragma unroll
        for (int j = 0; j < 8; ++j) a[j] = p4[tid + (it + j) * NT];
        #pragma unroll
        for (int j = 0; j < 8; ++j) {
            float xs[4] = {a[j].x, a[j].y, a[j].z, a[j].w};
            #pragma unroll
            for (int c = 0; c < 4; ++c) {
                float t = fabsf(xs[c] - med);
                if (binof(t, 0.0f, tsc) == (int)mbin) {
                    uint32_t pos = atomicAdd(&ctrl[8], 1u);
                    if (pos < MCAP) segs[pos] = __float_as_uint(t);
                }
            }
        }
    }
    __syncthreads();
    if (tid == 0) ctrl[11] = (ctrl[8] > MCAP || ctrl[8] != hist[mbin]) ? 1u : 0u;
    __syncthreads();
    if (ctrl[11]) { fb_path(p4, feat, row, hist, hist2, sbuf, out2, tid); return; }
    uint32_t madu = seg_select(segs, ctrl[8], mrem, hist2, sbuf, out2, tid);
    if (tid == 0) feat[row * 16 + 1] = __uint_as_float(madu);
}

// ---------- in-LDS bitonic sort of 512 floats, 256 threads ----------
__device__ void bitonic512(float* a, int tid) {
    for (int k = 2; k <= 512; k <<= 1) {
        for (int j = k >> 1; j > 0; j >>= 1) {
            __syncthreads();
            for (int i = tid; i < 512; i += 256) {
                int ixj = i ^ j;
                if (ixj > i) {
                    float x = a[i], y = a[ixj];
                    bool up = ((i & k) == 0);
                    if ((x > y) == up) { a[i] = y; a[ixj] = x; }
                }
            }
        }
    }
    __syncthreads();
}

// ---------- tail: b-row stats + MLP head fused, one block per (l,b) row ----------
__global__ __launch_bounds__(256) void tail_kernel(
    const float* __restrict__ bsrc, const float* __restrict__ feat,
    const float* __restrict__ fc1_w, const float* __restrict__ fc1_b,
    const float* __restrict__ ln_w,  const float* __restrict__ ln_b,
    const float* __restrict__ gate_w, const float* __restrict__ gate_b,
    const float* __restrict__ fco_w,  const float* __restrict__ fco_b,
    const float* __restrict__ scale,  float* __restrict__ out) {
    const int row = blockIdx.x;
    const int tid = threadIdx.x;
    const int l = row >> 6;
    __shared__ float a[512], d[512];
    __shared__ float x[16], h[64], hg[64], stats[2];

    if (tid < 7)       x[tid] = feat[row * 16 + tid];
    else if (tid == 7) x[14]  = feat[row * 16 + 14];
    else if (tid == 8) x[15]  = 0.0f;

    const float* p = bsrc + (size_t)row * 512;
    for (int i = tid; i < 512; i += 256) a[i] = p[i];
    bitonic512(a, tid);
    const float bmed = a[255];
    if (tid == 0) {
        x[7]  = bmed;
        x[9]  = a[0];
        x[10] = 0.25f * a[127] + 0.75f * a[128];
        x[11] = 0.5f  * (a[255] + a[256]);
        x[12] = 0.75f * a[383] + 0.25f * a[384];
        x[13] = a[511];
    }
    __syncthreads();
    for (int i = tid; i < 512; i += 256) d[i] = fabsf(a[i] - bmed);
    bitonic512(d, tid);
    if (tid == 0) x[8] = d[255];
    __syncthreads();

    if (tid == 0) {
        float mu = 0.f;
        for (int i = 0; i < 16; ++i) mu += x[i];
        mu *= (1.f / 16.f);
        float var = 0.f;
        for (int i = 0; i < 16; ++i) { float dd = x[i] - mu; var += dd * dd; }
        var *= (1.f / 16.f);
        stats[0] = mu; stats[1] = rsqrtf(var + 1e-5f);
    }
    __syncthreads();
    if (tid < 16) x[tid] = (x[tid] - stats[0]) * stats[1];
    __syncthreads();
    if (tid < 64) {
        const float* wv = fc1_w + ((size_t)l * 64 + tid) * 16;
        float acc = fc1_b[l * 64 + tid];
        #pragma unroll
        for (int i = 0; i < 16; ++i) acc += x[i] * wv[i];
        h[tid] = acc;
    }
    __syncthreads();
    if (tid == 0) {
        float mu = 0.f;
        for (int i = 0; i < 64; ++i) mu += h[i];
        mu *= (1.f / 64.f);
        float var = 0.f;
        for (int i = 0; i < 64; ++i) { float dd = h[i] - mu; var += dd * dd; }
        var *= (1.f / 64.f);
        stats[0] = mu; stats[1] = rsqrtf(var + 1e-5f);
    }
    __syncthreads();
    if (tid < 64) {
        float v = (h[tid] - stats[0]) * stats[1] * ln_w[l * 64 + tid] + ln_b[l * 64 + tid];
        h[tid] = 0.5f * v * (1.0f + erff(v * 0.70710678118654752f));
    }
    __syncthreads();
    if (tid < 64) {
        const float* wv = gate_w + ((size_t)l * 64 + tid) * 64;
        float acc = gate_b[l * 64 + tid];
        #pragma unroll
        for (int i = 0; i < 64; ++i) acc += h[i] * wv[i];
        float g = 1.0f / (1.0f + expf(-acc));
        hg[tid] = h[tid] * g;
    }
    __syncthreads();
    const float sc = scale[l];
    for (int o = tid; o < 512; o += 256) {
        const float* wv = fco_w + ((size_t)l * 512 + o) * 64;
        float acc = fco_b[l * 512 + o];
        #pragma unroll
        for (int i = 0; i < 64; ++i) acc += hg[i] * wv[i];
        out[(size_t)row * 512 + o] = sinf(acc) * sc + 1.0f;
    }
}

extern "C" void kernel_launch(void* const* d_in, const int* in_sizes, int n_in,
                              void* d_out, int out_size, void* d_ws, size_t ws_size,
                              hipStream_t stream) {
    const float* ws_in  = (const float*)d_in[0];
    const float* bs_in  = (const float*)d_in[1];
    const float* fc1_w  = (const float*)d_in[4];
    const float* fc1_b  = (const float*)d_in[5];
    const float* ln_w   = (const float*)d_in[6];
    const float* ln_b   = (const float*)d_in[7];
    const float* gate_w = (const float*)d_in[8];
    const float* gate_b = (const float*)d_in[9];
    const float* fco_w  = (const float*)d_in[10];
    const float* fco_b  = (const float*)d_in[11];
    const float* scale  = (const float*)d_in[12];
    float* out  = (float*)d_out;
    float* feat = (float*)d_ws;

    hipLaunchKernelGGL(wstats_kernel, dim3(NROW), dim3(NT), 0, stream, ws_in, feat);
    hipLaunchKernelGGL(tail_kernel, dim3(NROW), dim3(256), 0, stream,
                       bs_in, feat, fc1_w, fc1_b, ln_w, ln_b, gate_w, gate_b,
                       fco_w, fco_b, scale, out);
}